// Round 1
// baseline (3331.698 us; speedup 1.0000x reference)
//
#include <hip/hip_runtime.h>

#define DD 48
#define HW (48 * 48)
#define NV (48 * 48 * 48)   // 110592 voxels
#define COUT 32

// ---------------------------------------------------------------------------
// 3x3x3 SAME conv (zero pad), C_out = 81 offset channels.
// Thread = one voxel; blockIdx.y selects a chunk of 27 output channels.
// Weight/bias indices are wave-uniform -> scalar loads.
// ---------------------------------------------------------------------------
template <int CIN>
__global__ __launch_bounds__(256) void conv3_off_kernel(
    const float* __restrict__ x, const float* __restrict__ wt,
    const float* __restrict__ bias, float* __restrict__ out)
{
    const int v = blockIdx.x * 256 + threadIdx.x;
    const int co0 = blockIdx.y * 27;
    const int d = v / HW;
    const int rem = v % HW;
    const int h = rem / DD;
    const int wv = rem % DD;

    float acc[27];
#pragma unroll
    for (int i = 0; i < 27; ++i) acc[i] = bias[co0 + i];

    for (int tap = 0; tap < 27; ++tap) {
        const int dd = tap / 9 - 1;
        const int dh = (tap / 3) % 3 - 1;
        const int dw = tap % 3 - 1;
        const int zd = d + dd, zh = h + dh, zw = wv + dw;
        const bool ok = ((unsigned)zd < 48u) & ((unsigned)zh < 48u) & ((unsigned)zw < 48u);
        const int base = (zd * DD + zh) * DD + zw;
        for (int ci = 0; ci < CIN; ++ci) {
            const float xv = ok ? x[ci * NV + base] : 0.0f;
#pragma unroll
            for (int i = 0; i < 27; ++i)
                acc[i] += xv * wt[(co0 + i) * (CIN * 27) + ci * 27 + tap];
        }
    }
#pragma unroll
    for (int i = 0; i < 27; ++i) out[(co0 + i) * NV + v] = acc[i];
}

// ---------------------------------------------------------------------------
// Deformable conv: trilinear sample at p0 + p_n + offset (clamped), then
// contract over (C_in, 27) with conv weight. Thread = one voxel, acc[32].
// ---------------------------------------------------------------------------
template <int CIN>
__global__ __launch_bounds__(256) void deform_kernel(
    const float* __restrict__ x, const float* __restrict__ off,
    const float* __restrict__ wt, float* __restrict__ y)
{
    const int v = blockIdx.x * 256 + threadIdx.x;
    const int d = v / HW;
    const int rem = v % HW;
    const int h = rem / DD;
    const int wv = rem % DD;

    float acc[COUT];
#pragma unroll
    for (int i = 0; i < COUT; ++i) acc[i] = 0.0f;

    for (int k = 0; k < 27; ++k) {
        const float od = off[(0 * 27 + k) * NV + v];
        const float oh = off[(1 * 27 + k) * NV + v];
        const float ow = off[(2 * 27 + k) * NV + v];

        const int pnd = k / 9 - 1;
        const int pnh = (k / 3) % 3 - 1;
        const int pnw = k % 3 - 1;

        const float pd = fminf(fmaxf((float)(d + pnd) + od, 0.0f), 47.0f);
        const float ph = fminf(fmaxf((float)(h + pnh) + oh, 0.0f), 47.0f);
        const float pw = fminf(fmaxf((float)(wv + pnw) + ow, 0.0f), 47.0f);

        const float d0f = floorf(pd), h0f = floorf(ph), w0f = floorf(pw);
        const float fd = pd - d0f, fh = ph - h0f, fw = pw - w0f;
        const int d0 = (int)d0f, h0 = (int)h0f, w0 = (int)w0f;
        const int d1 = min(d0 + 1, 47), h1 = min(h0 + 1, 47), w1 = min(w0 + 1, 47);

        const float gd = 1.0f - fd, gh = 1.0f - fh, gw = 1.0f - fw;
        const float c000 = gd * gh * gw, c001 = gd * gh * fw;
        const float c010 = gd * fh * gw, c011 = gd * fh * fw;
        const float c100 = fd * gh * gw, c101 = fd * gh * fw;
        const float c110 = fd * fh * gw, c111 = fd * fh * fw;

        const int i000 = (d0 * DD + h0) * DD + w0, i001 = (d0 * DD + h0) * DD + w1;
        const int i010 = (d0 * DD + h1) * DD + w0, i011 = (d0 * DD + h1) * DD + w1;
        const int i100 = (d1 * DD + h0) * DD + w0, i101 = (d1 * DD + h0) * DD + w1;
        const int i110 = (d1 * DD + h1) * DD + w0, i111 = (d1 * DD + h1) * DD + w1;

        for (int ci = 0; ci < CIN; ++ci) {
            const float* xc = x + ci * NV;
            const float val = xc[i000] * c000 + xc[i001] * c001
                            + xc[i010] * c010 + xc[i011] * c011
                            + xc[i100] * c100 + xc[i101] * c101
                            + xc[i110] * c110 + xc[i111] * c111;
#pragma unroll
            for (int co = 0; co < COUT; ++co)
                acc[co] += val * wt[co * (CIN * 27) + ci * 27 + k];
        }
    }
#pragma unroll
    for (int co = 0; co < COUT; ++co) y[co * NV + v] = acc[co];
}

// ---------------------------------------------------------------------------
// BN stats (training mode, biased var): one block per channel.
// Produces fused scale/shift: out = max(0, y*sc + sh).
// ---------------------------------------------------------------------------
__global__ __launch_bounds__(1024) void bn_stats_kernel(
    const float* __restrict__ y, const float* __restrict__ gamma,
    const float* __restrict__ beta, float* __restrict__ sc, float* __restrict__ sh)
{
    const int c = blockIdx.x;
    const float* yc = y + c * NV;
    float s = 0.0f, s2 = 0.0f;
    for (int i = threadIdx.x; i < NV; i += 1024) {
        const float t = yc[i];
        s += t;
        s2 += t * t;
    }
    __shared__ float ls[1024], ls2[1024];
    ls[threadIdx.x] = s;
    ls2[threadIdx.x] = s2;
    __syncthreads();
    for (int st = 512; st > 0; st >>= 1) {
        if (threadIdx.x < st) {
            ls[threadIdx.x] += ls[threadIdx.x + st];
            ls2[threadIdx.x] += ls2[threadIdx.x + st];
        }
        __syncthreads();
    }
    if (threadIdx.x == 0) {
        const float mu = ls[0] * (1.0f / NV);
        const float var = ls2[0] * (1.0f / NV) - mu * mu;
        const float inv = rsqrtf(var + 1e-5f);
        sc[c] = gamma[c] * inv;
        sh[c] = beta[c] - mu * gamma[c] * inv;
    }
}

__global__ __launch_bounds__(256) void bn_apply_kernel(
    const float* __restrict__ y, const float* __restrict__ sc,
    const float* __restrict__ sh, float* __restrict__ out)
{
    const int i = blockIdx.x * 256 + threadIdx.x;        // float4 index
    const int c = (i * 4) / NV;                          // NV % 4 == 0
    const float a = sc[c], b = sh[c];
    float4 t = ((const float4*)y)[i];
    t.x = fmaxf(t.x * a + b, 0.0f);
    t.y = fmaxf(t.y * a + b, 0.0f);
    t.z = fmaxf(t.z * a + b, 0.0f);
    t.w = fmaxf(t.w * a + b, 0.0f);
    ((float4*)out)[i] = t;
}

// ---------------------------------------------------------------------------
extern "C" void kernel_launch(void* const* d_in, const int* in_sizes, int n_in,
                              void* d_out, int out_size, void* d_ws, size_t ws_size,
                              hipStream_t stream) {
    (void)in_sizes; (void)n_in; (void)out_size; (void)ws_size;

    const float* x      = (const float*)d_in[0];
    const float* w_off1 = (const float*)d_in[1];
    const float* b_off1 = (const float*)d_in[2];
    const float* w1     = (const float*)d_in[3];
    const float* gamma1 = (const float*)d_in[4];
    const float* beta1  = (const float*)d_in[5];
    const float* w_off2 = (const float*)d_in[6];
    const float* b_off2 = (const float*)d_in[7];
    const float* w2     = (const float*)d_in[8];
    const float* gamma2 = (const float*)d_in[9];
    const float* beta2  = (const float*)d_in[10];

    float* off = (float*)d_ws;           // 81 * NV
    float* y   = off + 81 * NV;          // 32 * NV
    float* h   = y + 32 * NV;            // 32 * NV
    float* sc  = h + 32 * NV;            // 32
    float* sh  = sc + 32;                // 32

    const int nvb = NV / 256;            // 432
    const int nel4 = (COUT * NV) / 4 / 256;  // 3456 blocks for bn_apply

    // ---- layer 1 ----
    conv3_off_kernel<16><<<dim3(nvb, 3), 256, 0, stream>>>(x, w_off1, b_off1, off);
    deform_kernel<16><<<nvb, 256, 0, stream>>>(x, off, w1, y);
    bn_stats_kernel<<<32, 1024, 0, stream>>>(y, gamma1, beta1, sc, sh);
    bn_apply_kernel<<<nel4, 256, 0, stream>>>(y, sc, sh, h);

    // ---- layer 2 ----
    conv3_off_kernel<32><<<dim3(nvb, 3), 256, 0, stream>>>(h, w_off2, b_off2, off);
    deform_kernel<32><<<nvb, 256, 0, stream>>>(h, off, w2, y);
    bn_stats_kernel<<<32, 1024, 0, stream>>>(y, gamma2, beta2, sc, sh);
    bn_apply_kernel<<<nel4, 256, 0, stream>>>(y, sc, sh, (float*)d_out);
}

// Round 2
// 1268.579 us; speedup vs baseline: 2.6263x; 2.6263x over previous
//
#include <hip/hip_runtime.h>

#define DD 48
#define HW (48 * 48)
#define NV (48 * 48 * 48)   // 110592 voxels
#define COUT 32

// ---------------------------------------------------------------------------
// Weight transpose: wt[co][ci][tap] -> wT[tap][ci][co]  (co contiguous so the
// wave-uniform scalar loads in the conv kernels hit 1-2 scalar-cache lines
// instead of 27 distinct lines per inner iteration).
// ---------------------------------------------------------------------------
__global__ __launch_bounds__(256) void transpose_w_kernel(
    const float* __restrict__ wt, float* __restrict__ wT, int COUTN, int CIN)
{
    const int i = blockIdx.x * 256 + threadIdx.x;
    const int total = COUTN * CIN * 27;
    if (i >= total) return;
    const int co = i / (CIN * 27);
    const int r = i % (CIN * 27);
    const int ci = r / 27;
    const int tap = r % 27;
    wT[(tap * CIN + ci) * COUTN + co] = wt[i];
}

// ---------------------------------------------------------------------------
// 3x3x3 SAME conv (zero pad), 81 offset channels, chunked 27 per blockIdx.y.
// Thread = one voxel. Weights pre-transposed to [tap][ci][co] (contiguous co).
// ---------------------------------------------------------------------------
template <int CIN>
__global__ __launch_bounds__(256) void conv3_off_kernel(
    const float* __restrict__ x, const float* __restrict__ wT,
    const float* __restrict__ bias, float* __restrict__ out)
{
    const int v = blockIdx.x * 256 + threadIdx.x;
    const int co0 = blockIdx.y * 27;
    const int d = v / HW;
    const int rem = v % HW;
    const int h = rem / DD;
    const int wv = rem % DD;

    float acc[27];
#pragma unroll
    for (int i = 0; i < 27; ++i) acc[i] = bias[co0 + i];

    int tap = 0;
    for (int dz = -1; dz <= 1; ++dz)
    for (int dy = -1; dy <= 1; ++dy)
    for (int dx = -1; dx <= 1; ++dx, ++tap) {
        const int zd = d + dz, zh = h + dy, zw = wv + dx;
        const bool ok = ((unsigned)zd < 48u) & ((unsigned)zh < 48u) & ((unsigned)zw < 48u);
        if (ok) {
            const int base = (zd * DD + zh) * DD + zw;
            const float* wrow = wT + (tap * CIN) * 81 + co0;
            for (int ci = 0; ci < CIN; ++ci) {
                const float xv = x[ci * NV + base];
                const float* wp = wrow + ci * 81;
#pragma unroll
                for (int i = 0; i < 27; ++i)
                    acc[i] += xv * wp[i];
            }
        }
    }
#pragma unroll
    for (int i = 0; i < 27; ++i) out[(co0 + i) * NV + v] = acc[i];
}

// ---------------------------------------------------------------------------
// Deformable conv: trilinear sample at p0 + p_n + offset (clamped), contract
// over (C_in, 27). Weights pre-transposed to [k][ci][co] (contiguous co).
// ---------------------------------------------------------------------------
template <int CIN>
__global__ __launch_bounds__(256) void deform_kernel(
    const float* __restrict__ x, const float* __restrict__ off,
    const float* __restrict__ wD, float* __restrict__ y)
{
    const int v = blockIdx.x * 256 + threadIdx.x;
    const int d = v / HW;
    const int rem = v % HW;
    const int h = rem / DD;
    const int wv = rem % DD;

    float acc[COUT];
#pragma unroll
    for (int i = 0; i < COUT; ++i) acc[i] = 0.0f;

    int k = 0;
    for (int dz = -1; dz <= 1; ++dz)
    for (int dy = -1; dy <= 1; ++dy)
    for (int dx = -1; dx <= 1; ++dx, ++k) {
        const float od = off[(0 * 27 + k) * NV + v];
        const float oh = off[(1 * 27 + k) * NV + v];
        const float ow = off[(2 * 27 + k) * NV + v];

        const float pd = fminf(fmaxf((float)(d + dz) + od, 0.0f), 47.0f);
        const float ph = fminf(fmaxf((float)(h + dy) + oh, 0.0f), 47.0f);
        const float pw = fminf(fmaxf((float)(wv + dx) + ow, 0.0f), 47.0f);

        const float d0f = floorf(pd), h0f = floorf(ph), w0f = floorf(pw);
        const float fd = pd - d0f, fh = ph - h0f, fw = pw - w0f;
        const int d0 = (int)d0f, h0 = (int)h0f, w0 = (int)w0f;
        const int sd = (d0 < 47) ? HW : 0;    // step to d1 (clamped)
        const int sh = (h0 < 47) ? DD : 0;    // step to h1
        const int sw = (w0 < 47) ? 1 : 0;     // step to w1

        const float gd = 1.0f - fd, gh = 1.0f - fh, gw = 1.0f - fw;
        const float c000 = gd * gh * gw, c001 = gd * gh * fw;
        const float c010 = gd * fh * gw, c011 = gd * fh * fw;
        const float c100 = fd * gh * gw, c101 = fd * gh * fw;
        const float c110 = fd * fh * gw, c111 = fd * fh * fw;

        const int i000 = (d0 * DD + h0) * DD + w0;
        const float* wrow = wD + (k * CIN) * COUT;

        for (int ci = 0; ci < CIN; ++ci) {
            const float* xc = x + ci * NV + i000;
            const float val = xc[0]           * c000 + xc[sw]           * c001
                            + xc[sh]          * c010 + xc[sh + sw]      * c011
                            + xc[sd]          * c100 + xc[sd + sw]      * c101
                            + xc[sd + sh]     * c110 + xc[sd + sh + sw] * c111;
            const float* wp = wrow + ci * COUT;
#pragma unroll
            for (int co = 0; co < COUT; ++co)
                acc[co] += val * wp[co];
        }
    }
#pragma unroll
    for (int co = 0; co < COUT; ++co) y[co * NV + v] = acc[co];
}

// ---------------------------------------------------------------------------
// BN stats (training mode, biased var): one block per channel.
// ---------------------------------------------------------------------------
__global__ __launch_bounds__(1024) void bn_stats_kernel(
    const float* __restrict__ y, const float* __restrict__ gamma,
    const float* __restrict__ beta, float* __restrict__ sc, float* __restrict__ sh)
{
    const int c = blockIdx.x;
    const float* yc = y + c * NV;
    float s = 0.0f, s2 = 0.0f;
    for (int i = threadIdx.x; i < NV; i += 1024) {
        const float t = yc[i];
        s += t;
        s2 += t * t;
    }
    __shared__ float ls[1024], ls2[1024];
    ls[threadIdx.x] = s;
    ls2[threadIdx.x] = s2;
    __syncthreads();
    for (int st = 512; st > 0; st >>= 1) {
        if (threadIdx.x < st) {
            ls[threadIdx.x] += ls[threadIdx.x + st];
            ls2[threadIdx.x] += ls2[threadIdx.x + st];
        }
        __syncthreads();
    }
    if (threadIdx.x == 0) {
        const float mu = ls[0] * (1.0f / NV);
        const float var = ls2[0] * (1.0f / NV) - mu * mu;
        const float inv = rsqrtf(var + 1e-5f);
        sc[c] = gamma[c] * inv;
        sh[c] = beta[c] - mu * gamma[c] * inv;
    }
}

__global__ __launch_bounds__(256) void bn_apply_kernel(
    const float* __restrict__ y, const float* __restrict__ sc,
    const float* __restrict__ sh, float* __restrict__ out)
{
    const int i = blockIdx.x * 256 + threadIdx.x;        // float4 index
    const int c = (i * 4) / NV;                          // NV % 4 == 0
    const float a = sc[c], b = sh[c];
    float4 t = ((const float4*)y)[i];
    t.x = fmaxf(t.x * a + b, 0.0f);
    t.y = fmaxf(t.y * a + b, 0.0f);
    t.z = fmaxf(t.z * a + b, 0.0f);
    t.w = fmaxf(t.w * a + b, 0.0f);
    ((float4*)out)[i] = t;
}

// ---------------------------------------------------------------------------
extern "C" void kernel_launch(void* const* d_in, const int* in_sizes, int n_in,
                              void* d_out, int out_size, void* d_ws, size_t ws_size,
                              hipStream_t stream) {
    (void)in_sizes; (void)n_in; (void)out_size; (void)ws_size;

    const float* x      = (const float*)d_in[0];
    const float* w_off1 = (const float*)d_in[1];
    const float* b_off1 = (const float*)d_in[2];
    const float* w1     = (const float*)d_in[3];
    const float* gamma1 = (const float*)d_in[4];
    const float* beta1  = (const float*)d_in[5];
    const float* w_off2 = (const float*)d_in[6];
    const float* b_off2 = (const float*)d_in[7];
    const float* w2     = (const float*)d_in[8];
    const float* gamma2 = (const float*)d_in[9];
    const float* beta2  = (const float*)d_in[10];

    float* off  = (float*)d_ws;           // 81 * NV
    float* y    = off + 81 * NV;          // 32 * NV
    float* h    = y + 32 * NV;            // 32 * NV
    float* sc   = h + 32 * NV;            // 32
    float* sh   = sc + 32;                // 32
    float* wT1  = sh + 32;                // 27*16*81 = 34992
    float* wT2  = wT1 + 27 * 16 * 81;     // 27*32*81 = 69984
    float* wD1  = wT2 + 27 * 32 * 81;     // 27*16*32 = 13824
    float* wD2  = wD1 + 27 * 16 * 32;     // 27*32*32 = 27648

    const int nvb = NV / 256;                 // 432
    const int nel4 = (COUT * NV) / 4 / 256;   // 3456 blocks for bn_apply

    // ---- weight transposes (tiny) ----
    transpose_w_kernel<<<(81 * 16 * 27 + 255) / 256, 256, 0, stream>>>(w_off1, wT1, 81, 16);
    transpose_w_kernel<<<(81 * 32 * 27 + 255) / 256, 256, 0, stream>>>(w_off2, wT2, 81, 32);
    transpose_w_kernel<<<(32 * 16 * 27 + 255) / 256, 256, 0, stream>>>(w1, wD1, 32, 16);
    transpose_w_kernel<<<(32 * 32 * 27 + 255) / 256, 256, 0, stream>>>(w2, wD2, 32, 32);

    // ---- layer 1 ----
    conv3_off_kernel<16><<<dim3(nvb, 3), 256, 0, stream>>>(x, wT1, b_off1, off);
    deform_kernel<16><<<nvb, 256, 0, stream>>>(x, off, wD1, y);
    bn_stats_kernel<<<32, 1024, 0, stream>>>(y, gamma1, beta1, sc, sh);
    bn_apply_kernel<<<nel4, 256, 0, stream>>>(y, sc, sh, h);

    // ---- layer 2 ----
    conv3_off_kernel<32><<<dim3(nvb, 3), 256, 0, stream>>>(h, wT2, b_off2, off);
    deform_kernel<32><<<nvb, 256, 0, stream>>>(h, off, wD2, y);
    bn_stats_kernel<<<32, 1024, 0, stream>>>(y, gamma2, beta2, sc, sh);
    bn_apply_kernel<<<nel4, 256, 0, stream>>>(y, sc, sh, (float*)d_out);
}

// Round 3
// 1228.947 us; speedup vs baseline: 2.7110x; 1.0322x over previous
//
#include <hip/hip_runtime.h>

#define DD 48
#define HW (48 * 48)
#define NV (48 * 48 * 48)   // 110592 voxels
#define COUT 32

typedef _Float16 h16;

// ---------------------------------------------------------------------------
// Weight transpose: wt[co][ci][tap] -> wT[tap][ci][co]  (co contiguous so the
// wave-uniform scalar loads in the conv kernels hit 1-2 scalar-cache lines).
// ---------------------------------------------------------------------------
__global__ __launch_bounds__(256) void transpose_w_kernel(
    const float* __restrict__ wt, float* __restrict__ wT, int COUTN, int CIN)
{
    const int i = blockIdx.x * 256 + threadIdx.x;
    const int total = COUTN * CIN * 27;
    if (i >= total) return;
    const int co = i / (CIN * 27);
    const int r = i % (CIN * 27);
    const int ci = r / 27;
    const int tap = r % 27;
    wT[(tap * CIN + ci) * COUTN + co] = wt[i];
}

// ---------------------------------------------------------------------------
// 3x3x3 SAME conv (zero pad), 81 offset channels, chunked 27 per blockIdx.y.
// Output stored as fp16 (offsets are O(0.3); pos error ~3e-4 << tolerance).
// ---------------------------------------------------------------------------
template <int CIN>
__global__ __launch_bounds__(256) void conv3_off_kernel(
    const float* __restrict__ x, const float* __restrict__ wT,
    const float* __restrict__ bias, h16* __restrict__ out)
{
    const int v = blockIdx.x * 256 + threadIdx.x;
    const int co0 = blockIdx.y * 27;
    const int d = v / HW;
    const int rem = v % HW;
    const int h = rem / DD;
    const int wv = rem % DD;

    float acc[27];
#pragma unroll
    for (int i = 0; i < 27; ++i) acc[i] = bias[co0 + i];

    int tap = 0;
    for (int dz = -1; dz <= 1; ++dz)
    for (int dy = -1; dy <= 1; ++dy)
    for (int dx = -1; dx <= 1; ++dx, ++tap) {
        const int zd = d + dz, zh = h + dy, zw = wv + dx;
        const bool ok = ((unsigned)zd < 48u) & ((unsigned)zh < 48u) & ((unsigned)zw < 48u);
        if (ok) {
            const int base = (zd * DD + zh) * DD + zw;
            const float* wrow = wT + (tap * CIN) * 81 + co0;
            for (int ci = 0; ci < CIN; ++ci) {
                const float xv = x[ci * NV + base];
                const float* wp = wrow + ci * 81;
#pragma unroll
                for (int i = 0; i < 27; ++i)
                    acc[i] += xv * wp[i];
            }
        }
    }
#pragma unroll
    for (int i = 0; i < 27; ++i) out[(co0 + i) * NV + v] = (h16)acc[i];
}

// ---------------------------------------------------------------------------
// Deformable conv, split-K over the 3 dz-planes of taps (blockIdx.y = plane).
// Each block accumulates 9 taps into a fp32 partial buffer.
// ---------------------------------------------------------------------------
template <int CIN>
__global__ __launch_bounds__(256) void deform_part_kernel(
    const float* __restrict__ x, const h16* __restrict__ off,
    const float* __restrict__ wD, float* __restrict__ part)
{
    const int v = blockIdx.x * 256 + threadIdx.x;
    const int g = blockIdx.y;            // dz-plane group: taps 9g..9g+8
    const int d = v / HW;
    const int rem = v % HW;
    const int h = rem / DD;
    const int wv = rem % DD;
    const int dz = g - 1;

    float acc[COUT];
#pragma unroll
    for (int i = 0; i < COUT; ++i) acc[i] = 0.0f;

#pragma unroll
    for (int j = 0; j < 9; ++j) {
        const int k = 9 * g + j;
        const int dy = j / 3 - 1;
        const int dx = j % 3 - 1;

        const float od = (float)off[(0 * 27 + k) * NV + v];
        const float oh = (float)off[(1 * 27 + k) * NV + v];
        const float ow = (float)off[(2 * 27 + k) * NV + v];

        const float pd = fminf(fmaxf((float)(d + dz) + od, 0.0f), 47.0f);
        const float ph = fminf(fmaxf((float)(h + dy) + oh, 0.0f), 47.0f);
        const float pw = fminf(fmaxf((float)(wv + dx) + ow, 0.0f), 47.0f);

        const float d0f = floorf(pd), h0f = floorf(ph), w0f = floorf(pw);
        const float fd = pd - d0f, fh = ph - h0f, fw = pw - w0f;
        const int d0 = (int)d0f, h0 = (int)h0f, w0 = (int)w0f;
        const int sd = (d0 < 47) ? HW : 0;    // step to d1 (clamped)
        const int sh = (h0 < 47) ? DD : 0;    // step to h1
        const int sw = (w0 < 47) ? 1 : 0;     // step to w1

        const float gd = 1.0f - fd, gh = 1.0f - fh, gw = 1.0f - fw;
        const float c000 = gd * gh * gw, c001 = gd * gh * fw;
        const float c010 = gd * fh * gw, c011 = gd * fh * fw;
        const float c100 = fd * gh * gw, c101 = fd * gh * fw;
        const float c110 = fd * fh * gw, c111 = fd * fh * fw;

        const int i000 = (d0 * DD + h0) * DD + w0;
        const float* wrow = wD + (k * CIN) * COUT;

        for (int ci = 0; ci < CIN; ++ci) {
            const float* xc = x + ci * NV + i000;
            const float val = xc[0]           * c000 + xc[sw]           * c001
                            + xc[sh]          * c010 + xc[sh + sw]      * c011
                            + xc[sd]          * c100 + xc[sd + sw]      * c101
                            + xc[sd + sh]     * c110 + xc[sd + sh + sw] * c111;
            const float* wp = wrow + ci * COUT;
#pragma unroll
            for (int co = 0; co < COUT; ++co)
                acc[co] += val * wp[co];
        }
    }
#pragma unroll
    for (int co = 0; co < COUT; ++co)
        part[(g * COUT + co) * NV + v] = acc[co];
}

// Sum the 3 split-K partials (float4).
__global__ __launch_bounds__(256) void reduce3_kernel(
    const float* __restrict__ part, float* __restrict__ y)
{
    const int i = blockIdx.x * 256 + threadIdx.x;   // float4 index, 32*NV/4 total
    const int stride = COUT * NV / 4;
    const float4 a = ((const float4*)part)[i];
    const float4 b = ((const float4*)part)[i + stride];
    const float4 c = ((const float4*)part)[i + 2 * stride];
    float4 r;
    r.x = a.x + b.x + c.x;
    r.y = a.y + b.y + c.y;
    r.z = a.z + b.z + c.z;
    r.w = a.w + b.w + c.w;
    ((float4*)y)[i] = r;
}

// ---------------------------------------------------------------------------
// BN stats (training mode, biased var): one block per channel.
// ---------------------------------------------------------------------------
__global__ __launch_bounds__(1024) void bn_stats_kernel(
    const float* __restrict__ y, const float* __restrict__ gamma,
    const float* __restrict__ beta, float* __restrict__ sc, float* __restrict__ sh)
{
    const int c = blockIdx.x;
    const float* yc = y + c * NV;
    float s = 0.0f, s2 = 0.0f;
    for (int i = threadIdx.x; i < NV; i += 1024) {
        const float t = yc[i];
        s += t;
        s2 += t * t;
    }
    __shared__ float ls[1024], ls2[1024];
    ls[threadIdx.x] = s;
    ls2[threadIdx.x] = s2;
    __syncthreads();
    for (int st = 512; st > 0; st >>= 1) {
        if (threadIdx.x < st) {
            ls[threadIdx.x] += ls[threadIdx.x + st];
            ls2[threadIdx.x] += ls2[threadIdx.x + st];
        }
        __syncthreads();
    }
    if (threadIdx.x == 0) {
        const float mu = ls[0] * (1.0f / NV);
        const float var = ls2[0] * (1.0f / NV) - mu * mu;
        const float inv = rsqrtf(var + 1e-5f);
        sc[c] = gamma[c] * inv;
        sh[c] = beta[c] - mu * gamma[c] * inv;
    }
}

__global__ __launch_bounds__(256) void bn_apply_kernel(
    const float* __restrict__ y, const float* __restrict__ sc,
    const float* __restrict__ sh, float* __restrict__ out)
{
    const int i = blockIdx.x * 256 + threadIdx.x;        // float4 index
    const int c = (i * 4) / NV;                          // NV % 4 == 0
    const float a = sc[c], b = sh[c];
    float4 t = ((const float4*)y)[i];
    t.x = fmaxf(t.x * a + b, 0.0f);
    t.y = fmaxf(t.y * a + b, 0.0f);
    t.z = fmaxf(t.z * a + b, 0.0f);
    t.w = fmaxf(t.w * a + b, 0.0f);
    ((float4*)out)[i] = t;
}

// ---------------------------------------------------------------------------
extern "C" void kernel_launch(void* const* d_in, const int* in_sizes, int n_in,
                              void* d_out, int out_size, void* d_ws, size_t ws_size,
                              hipStream_t stream) {
    (void)in_sizes; (void)n_in; (void)out_size; (void)ws_size;

    const float* x      = (const float*)d_in[0];
    const float* w_off1 = (const float*)d_in[1];
    const float* b_off1 = (const float*)d_in[2];
    const float* w1     = (const float*)d_in[3];
    const float* gamma1 = (const float*)d_in[4];
    const float* beta1  = (const float*)d_in[5];
    const float* w_off2 = (const float*)d_in[6];
    const float* b_off2 = (const float*)d_in[7];
    const float* w2     = (const float*)d_in[8];
    const float* gamma2 = (const float*)d_in[9];
    const float* beta2  = (const float*)d_in[10];

    char* ws = (char*)d_ws;
    h16*   off  = (h16*)ws;                 ws += (size_t)81 * NV * sizeof(h16);
    float* y    = (float*)ws;               ws += (size_t)32 * NV * sizeof(float);
    float* h    = (float*)ws;               ws += (size_t)32 * NV * sizeof(float);
    float* part = (float*)ws;               ws += (size_t)3 * 32 * NV * sizeof(float);
    float* sc   = (float*)ws;               ws += 32 * sizeof(float);
    float* sh   = (float*)ws;               ws += 32 * sizeof(float);
    float* wT1  = (float*)ws;               ws += (size_t)27 * 16 * 81 * sizeof(float);
    float* wT2  = (float*)ws;               ws += (size_t)27 * 32 * 81 * sizeof(float);
    float* wD1  = (float*)ws;               ws += (size_t)27 * 16 * 32 * sizeof(float);
    float* wD2  = (float*)ws;               ws += (size_t)27 * 32 * 32 * sizeof(float);

    const int nvb = NV / 256;                 // 432
    const int nel4 = (COUT * NV) / 4 / 256;   // 3456 blocks (float4 grids)

    // ---- weight transposes (tiny) ----
    transpose_w_kernel<<<(81 * 16 * 27 + 255) / 256, 256, 0, stream>>>(w_off1, wT1, 81, 16);
    transpose_w_kernel<<<(81 * 32 * 27 + 255) / 256, 256, 0, stream>>>(w_off2, wT2, 81, 32);
    transpose_w_kernel<<<(32 * 16 * 27 + 255) / 256, 256, 0, stream>>>(w1, wD1, 32, 16);
    transpose_w_kernel<<<(32 * 32 * 27 + 255) / 256, 256, 0, stream>>>(w2, wD2, 32, 32);

    // ---- layer 1 ----
    conv3_off_kernel<16><<<dim3(nvb, 3), 256, 0, stream>>>(x, wT1, b_off1, off);
    deform_part_kernel<16><<<dim3(nvb, 3), 256, 0, stream>>>(x, off, wD1, part);
    reduce3_kernel<<<nel4, 256, 0, stream>>>(part, y);
    bn_stats_kernel<<<32, 1024, 0, stream>>>(y, gamma1, beta1, sc, sh);
    bn_apply_kernel<<<nel4, 256, 0, stream>>>(y, sc, sh, h);

    // ---- layer 2 ----
    conv3_off_kernel<32><<<dim3(nvb, 3), 256, 0, stream>>>(h, wT2, b_off2, off);
    deform_part_kernel<32><<<dim3(nvb, 3), 256, 0, stream>>>(h, off, wD2, part);
    reduce3_kernel<<<nel4, 256, 0, stream>>>(part, y);
    bn_stats_kernel<<<32, 1024, 0, stream>>>(y, gamma2, beta2, sc, sh);
    bn_apply_kernel<<<nel4, 256, 0, stream>>>(y, sc, sh, (float*)d_out);
}

// Round 4
// 789.228 us; speedup vs baseline: 4.2215x; 1.5572x over previous
//
#include <hip/hip_runtime.h>

#define DD 48
#define HW (48 * 48)
#define NV (48 * 48 * 48)   // 110592 voxels
#define COUT 32

// deform tile geometry
#define TD 4
#define TH 8
#define TW 8
#define RD (TD + 4)         // 8   (halo +-2)
#define RH (TH + 4)         // 12
#define RW (TW + 4)         // 12
#define REGN (RD * RH * RW) // 1152 floats per channel
#define NCH 8               // channels staged per chunk

typedef _Float16 h16;

// ---------------------------------------------------------------------------
// Weight transpose: wt[co][ci][tap] -> wT[tap][ci][co]  (co contiguous so the
// wave-uniform scalar loads in the conv kernels hit 1-2 scalar-cache lines).
// ---------------------------------------------------------------------------
__global__ __launch_bounds__(256) void transpose_w_kernel(
    const float* __restrict__ wt, float* __restrict__ wT, int COUTN, int CIN)
{
    const int i = blockIdx.x * 256 + threadIdx.x;
    const int total = COUTN * CIN * 27;
    if (i >= total) return;
    const int co = i / (CIN * 27);
    const int r = i % (CIN * 27);
    const int ci = r / 27;
    const int tap = r % 27;
    wT[(tap * CIN + ci) * COUTN + co] = wt[i];
}

// ---------------------------------------------------------------------------
// 3x3x3 SAME conv (zero pad), 81 offset channels, chunked 27 per blockIdx.y.
// Output stored as fp16 (offsets are O(0.3); pos error ~3e-4 << tolerance).
// ---------------------------------------------------------------------------
template <int CIN>
__global__ __launch_bounds__(256) void conv3_off_kernel(
    const float* __restrict__ x, const float* __restrict__ wT,
    const float* __restrict__ bias, h16* __restrict__ out)
{
    const int v = blockIdx.x * 256 + threadIdx.x;
    const int co0 = blockIdx.y * 27;
    const int d = v / HW;
    const int rem = v % HW;
    const int h = rem / DD;
    const int wv = rem % DD;

    float acc[27];
#pragma unroll
    for (int i = 0; i < 27; ++i) acc[i] = bias[co0 + i];

    int tap = 0;
    for (int dz = -1; dz <= 1; ++dz)
    for (int dy = -1; dy <= 1; ++dy)
    for (int dx = -1; dx <= 1; ++dx, ++tap) {
        const int zd = d + dz, zh = h + dy, zw = wv + dx;
        const bool ok = ((unsigned)zd < 48u) & ((unsigned)zh < 48u) & ((unsigned)zw < 48u);
        if (ok) {
            const int base = (zd * DD + zh) * DD + zw;
            const float* wrow = wT + (tap * CIN) * 81 + co0;
            for (int ci = 0; ci < CIN; ++ci) {
                const float xv = x[ci * NV + base];
                const float* wp = wrow + ci * 81;
#pragma unroll
                for (int i = 0; i < 27; ++i)
                    acc[i] += xv * wp[i];
            }
        }
    }
#pragma unroll
    for (int i = 0; i < 27; ++i) out[(co0 + i) * NV + v] = (h16)acc[i];
}

// ---------------------------------------------------------------------------
// Deformable conv, LDS-tiled: block = 4x8x8 voxel tile, blockIdx.y = chunk of
// NCH input channels. The tile+halo(+-2) region of x for NCH channels is
// staged in LDS once and reused by all 27 taps (kills the per-tap re-fetch
// of x from HBM). Rare samples escaping the halo fall back to global loads.
// ---------------------------------------------------------------------------
template <int CIN>
__global__ __launch_bounds__(256) void deform_tile_kernel(
    const float* __restrict__ x, const h16* __restrict__ off,
    const float* __restrict__ wD, float* __restrict__ part)
{
    __shared__ float reg[NCH][REGN];   // 36864 B

    const int t = threadIdx.x;
    const int bx = blockIdx.x;               // 432 tiles
    const int tilew = bx % 6;
    const int tileh = (bx / 6) % 6;
    const int tiled = bx / 36;               // 0..11
    const int chunk = blockIdx.y;
    const int c0 = chunk * NCH;

    const int tz = t >> 6, ty = (t >> 3) & 7, tx = t & 7;
    const int d  = tiled * TD + tz;
    const int hh = tileh * TH + ty;
    const int ww = tilew * TW + tx;
    const int v  = (d * DD + hh) * DD + ww;

    const int dlo = tiled * TD - 2;
    const int hlo = tileh * TH - 2;
    const int wlo = tilew * TW - 2;

    // ---- stage x region for NCH channels ----
    for (int i = t; i < NCH * REGN; i += 256) {
        const int ci = i / REGN;
        const int r  = i % REGN;
        const int rz = r / (RH * RW);
        const int rr = r % (RH * RW);
        const int ry = rr / RW, rx = rr % RW;
        const int gz = min(max(dlo + rz, 0), 47);
        const int gy = min(max(hlo + ry, 0), 47);
        const int gx = min(max(wlo + rx, 0), 47);
        reg[ci][r] = x[(c0 + ci) * NV + (gz * DD + gy) * DD + gx];
    }
    __syncthreads();

    float acc[COUT];
#pragma unroll
    for (int i = 0; i < COUT; ++i) acc[i] = 0.0f;

    for (int k = 0; k < 27; ++k) {
        const int dz = k / 9 - 1;
        const int dy = (k / 3) % 3 - 1;
        const int dx = k % 3 - 1;

        const float od = (float)off[(0 * 27 + k) * NV + v];
        const float oh = (float)off[(1 * 27 + k) * NV + v];
        const float ow = (float)off[(2 * 27 + k) * NV + v];

        const float pd = fminf(fmaxf((float)(d + dz) + od, 0.0f), 47.0f);
        const float ph = fminf(fmaxf((float)(hh + dy) + oh, 0.0f), 47.0f);
        const float pw = fminf(fmaxf((float)(ww + dx) + ow, 0.0f), 47.0f);

        const float d0f = floorf(pd), h0f = floorf(ph), w0f = floorf(pw);
        const float fd = pd - d0f, fh = ph - h0f, fw = pw - w0f;
        const int d0 = (int)d0f, h0 = (int)h0f, w0 = (int)w0f;
        const int dst = (d0 < 47) ? 1 : 0;   // d1 - d0
        const int hst = (h0 < 47) ? 1 : 0;
        const int wst = (w0 < 47) ? 1 : 0;

        const float gd = 1.0f - fd, gh = 1.0f - fh, gw = 1.0f - fw;
        const float c000 = gd * gh * gw, c001 = gd * gh * fw;
        const float c010 = gd * fh * gw, c011 = gd * fh * fw;
        const float c100 = fd * gh * gw, c101 = fd * gh * fw;
        const float c110 = fd * fh * gw, c111 = fd * fh * fw;

        const float* wrow = wD + (k * CIN + c0) * COUT;

        const int ld = d0 - dlo, lh = h0 - hlo, lw = w0 - wlo;
        const bool inreg = (ld >= 0) & (ld + dst <= RD - 1)
                         & (lh >= 0) & (lh + hst <= RH - 1)
                         & (lw >= 0) & (lw + wst <= RW - 1);

        if (inreg) {
            const int base = (ld * RH + lh) * RW + lw;
            const int zs = dst ? RH * RW : 0;
            const int ys = hst ? RW : 0;
            const int xs = wst;
#pragma unroll
            for (int ci = 0; ci < NCH; ++ci) {
                const float* xc = &reg[ci][base];
                const float val = xc[0]       * c000 + xc[xs]           * c001
                                + xc[ys]      * c010 + xc[ys + xs]      * c011
                                + xc[zs]      * c100 + xc[zs + xs]      * c101
                                + xc[zs + ys] * c110 + xc[zs + ys + xs] * c111;
                const float* wp = wrow + ci * COUT;
#pragma unroll
                for (int co = 0; co < COUT; ++co)
                    acc[co] += val * wp[co];
            }
        } else {
            const int i000 = (d0 * DD + h0) * DD + w0;
            const int sd = dst ? HW : 0, sh = hst ? DD : 0, sw = wst;
#pragma unroll
            for (int ci = 0; ci < NCH; ++ci) {
                const float* xc = x + (c0 + ci) * NV + i000;
                const float val = xc[0]       * c000 + xc[sw]           * c001
                                + xc[sh]      * c010 + xc[sh + sw]      * c011
                                + xc[sd]      * c100 + xc[sd + sw]      * c101
                                + xc[sd + sh] * c110 + xc[sd + sh + sw] * c111;
                const float* wp = wrow + ci * COUT;
#pragma unroll
                for (int co = 0; co < COUT; ++co)
                    acc[co] += val * wp[co];
            }
        }
    }

#pragma unroll
    for (int co = 0; co < COUT; ++co)
        part[(chunk * COUT + co) * NV + v] = acc[co];
}

// Sum NC split-K partials (float4).
template <int NC>
__global__ __launch_bounds__(256) void reduceN_kernel(
    const float* __restrict__ part, float* __restrict__ y)
{
    const int i = blockIdx.x * 256 + threadIdx.x;   // float4 index
    const int stride = COUT * NV / 4;
    float4 a = ((const float4*)part)[i];
#pragma unroll
    for (int c = 1; c < NC; ++c) {
        const float4 b = ((const float4*)part)[i + c * stride];
        a.x += b.x; a.y += b.y; a.z += b.z; a.w += b.w;
    }
    ((float4*)y)[i] = a;
}

// ---------------------------------------------------------------------------
// BN stats (training mode, biased var): one block per channel.
// ---------------------------------------------------------------------------
__global__ __launch_bounds__(1024) void bn_stats_kernel(
    const float* __restrict__ y, const float* __restrict__ gamma,
    const float* __restrict__ beta, float* __restrict__ sc, float* __restrict__ sh)
{
    const int c = blockIdx.x;
    const float* yc = y + c * NV;
    float s = 0.0f, s2 = 0.0f;
    for (int i = threadIdx.x; i < NV; i += 1024) {
        const float t = yc[i];
        s += t;
        s2 += t * t;
    }
    __shared__ float ls[1024], ls2[1024];
    ls[threadIdx.x] = s;
    ls2[threadIdx.x] = s2;
    __syncthreads();
    for (int st = 512; st > 0; st >>= 1) {
        if (threadIdx.x < st) {
            ls[threadIdx.x] += ls[threadIdx.x + st];
            ls2[threadIdx.x] += ls2[threadIdx.x + st];
        }
        __syncthreads();
    }
    if (threadIdx.x == 0) {
        const float mu = ls[0] * (1.0f / NV);
        const float var = ls2[0] * (1.0f / NV) - mu * mu;
        const float inv = rsqrtf(var + 1e-5f);
        sc[c] = gamma[c] * inv;
        sh[c] = beta[c] - mu * gamma[c] * inv;
    }
}

__global__ __launch_bounds__(256) void bn_apply_kernel(
    const float* __restrict__ y, const float* __restrict__ sc,
    const float* __restrict__ sh, float* __restrict__ out)
{
    const int i = blockIdx.x * 256 + threadIdx.x;        // float4 index
    const int c = (i * 4) / NV;                          // NV % 4 == 0
    const float a = sc[c], b = sh[c];
    float4 t = ((const float4*)y)[i];
    t.x = fmaxf(t.x * a + b, 0.0f);
    t.y = fmaxf(t.y * a + b, 0.0f);
    t.z = fmaxf(t.z * a + b, 0.0f);
    t.w = fmaxf(t.w * a + b, 0.0f);
    ((float4*)out)[i] = t;
}

// ---------------------------------------------------------------------------
extern "C" void kernel_launch(void* const* d_in, const int* in_sizes, int n_in,
                              void* d_out, int out_size, void* d_ws, size_t ws_size,
                              hipStream_t stream) {
    (void)in_sizes; (void)n_in; (void)out_size; (void)ws_size;

    const float* x      = (const float*)d_in[0];
    const float* w_off1 = (const float*)d_in[1];
    const float* b_off1 = (const float*)d_in[2];
    const float* w1     = (const float*)d_in[3];
    const float* gamma1 = (const float*)d_in[4];
    const float* beta1  = (const float*)d_in[5];
    const float* w_off2 = (const float*)d_in[6];
    const float* b_off2 = (const float*)d_in[7];
    const float* w2     = (const float*)d_in[8];
    const float* gamma2 = (const float*)d_in[9];
    const float* beta2  = (const float*)d_in[10];

    char* ws = (char*)d_ws;
    h16*   off  = (h16*)ws;                 ws += (size_t)81 * NV * sizeof(h16);
    float* y    = (float*)ws;               ws += (size_t)32 * NV * sizeof(float);
    float* h    = (float*)ws;               ws += (size_t)32 * NV * sizeof(float);
    float* part = (float*)ws;               ws += (size_t)4 * 32 * NV * sizeof(float);
    float* sc   = (float*)ws;               ws += 32 * sizeof(float);
    float* sh   = (float*)ws;               ws += 32 * sizeof(float);
    float* wT1  = (float*)ws;               ws += (size_t)27 * 16 * 81 * sizeof(float);
    float* wT2  = (float*)ws;               ws += (size_t)27 * 32 * 81 * sizeof(float);
    float* wD1  = (float*)ws;               ws += (size_t)27 * 16 * 32 * sizeof(float);
    float* wD2  = (float*)ws;               ws += (size_t)27 * 32 * 32 * sizeof(float);

    const int nvb = NV / 256;                 // 432
    const int nel4 = (COUT * NV) / 4 / 256;   // 3456 blocks (float4 grids)
    const int ntile = 432;                    // 12 * 6 * 6

    // ---- weight transposes (tiny) ----
    transpose_w_kernel<<<(81 * 16 * 27 + 255) / 256, 256, 0, stream>>>(w_off1, wT1, 81, 16);
    transpose_w_kernel<<<(81 * 32 * 27 + 255) / 256, 256, 0, stream>>>(w_off2, wT2, 81, 32);
    transpose_w_kernel<<<(32 * 16 * 27 + 255) / 256, 256, 0, stream>>>(w1, wD1, 32, 16);
    transpose_w_kernel<<<(32 * 32 * 27 + 255) / 256, 256, 0, stream>>>(w2, wD2, 32, 32);

    // ---- layer 1 ----
    conv3_off_kernel<16><<<dim3(nvb, 3), 256, 0, stream>>>(x, wT1, b_off1, off);
    deform_tile_kernel<16><<<dim3(ntile, 2), 256, 0, stream>>>(x, off, wD1, part);
    reduceN_kernel<2><<<nel4, 256, 0, stream>>>(part, y);
    bn_stats_kernel<<<32, 1024, 0, stream>>>(y, gamma1, beta1, sc, sh);
    bn_apply_kernel<<<nel4, 256, 0, stream>>>(y, sc, sh, h);

    // ---- layer 2 ----
    conv3_off_kernel<32><<<dim3(nvb, 3), 256, 0, stream>>>(h, wT2, b_off2, off);
    deform_tile_kernel<32><<<dim3(ntile, 4), 256, 0, stream>>>(h, off, wD2, part);
    reduceN_kernel<4><<<nel4, 256, 0, stream>>>(part, y);
    bn_stats_kernel<<<32, 1024, 0, stream>>>(y, gamma2, beta2, sc, sh);
    bn_apply_kernel<<<nel4, 256, 0, stream>>>(y, sc, sh, (float*)d_out);
}